// Round 1
// 730.240 us; speedup vs baseline: 1.1718x; 1.1718x over previous
//
#include <hip/hip_runtime.h>
#include <hip/hip_bf16.h>

using bf16x8 = __attribute__((ext_vector_type(8))) short;
using f32x4  = __attribute__((ext_vector_type(4))) float;

constexpr int Bn = 32;          // batch
constexpr int Tn = 2048;        // time
constexpr int Fn = 1024;        // feature dim (K)
constexpr int Vn = 256;         // vocab (N)
constexpr int Sn = 256;         // target len
constexpr int Ln = 2 * Sn + 1;  // 513 extended labels
constexpr int Mn = Bn * Tn;     // 65536 GEMM rows
constexpr int Lpad = 520;       // padded G row
constexpr int DQ = 16;          // prefetch depth; 32-step chunks % 16 == 0 keeps pl[] static

#define NEGF (-1e30f)

__device__ __forceinline__ float exp2fast(float x) { return __builtin_amdgcn_exp2f(x); }
__device__ __forceinline__ float log2fast(float x) { return __builtin_amdgcn_logf(x); }

// v_cvt_pk_bf16_f32: RNE, src0 -> low half (1 instr for 2 elems)
__device__ __forceinline__ unsigned int cvt_pk_bf16(float lo, float hi) {
    unsigned int r;
    asm("v_cvt_pk_bf16_f32 %0, %1, %2" : "=v"(r) : "v"(lo), "v"(hi));
    return r;
}

// log-add-exp in log2 domain. The max term's exp2 is exactly 1.0 -> folded to
// the literal (saves one trans op per call; bit-identical to exp2(0)).
__device__ __forceinline__ float lae2(float x, float y) {
    float m = fmaxf(x, y);
    float d = fminf(x, y) - m;
    return m + log2fast(1.0f + exp2fast(d));
}
__device__ __forceinline__ float lae3(float x, float y, float z) {
    float m  = fmaxf(fmaxf(x, y), z);              // v_max3_f32
    float md = __builtin_amdgcn_fmed3f(x, y, z);   // v_med3_f32
    float mn = fminf(fminf(x, y), z);              // v_min3_f32
    return m + log2fast(1.0f + exp2fast(md - m) + exp2fast(mn - m));
}

// ---------------- W fp32 -> bf16 pre-convert (once; Wb aliases head of G) ----
__global__ __launch_bounds__(256) void wcvt(const float* __restrict__ W,
                                            unsigned short* __restrict__ Wb)
{
    const int idx = (blockIdx.x * 256 + threadIdx.x) * 4;
    float4 v = *reinterpret_cast<const float4*>(W + idx);
    uint2 p;
    p.x = cvt_pk_bf16(v.x, v.y);
    p.y = cvt_pk_bf16(v.z, v.w);
    *reinterpret_cast<uint2*>(Wb + idx) = p;
}

// ---------------- GEMM: logits = features @ W^T + bias (bf16 MFMA) ----------
// 512 threads (8 waves: 2 wm x 4 wn), tile 128x256, BK=64.
// sA: reg-staged f32->bf16 via v_cvt_pk; sB: global_load_lds width=16 of
// pre-converted Wb. Both LDS tiles XOR-swizzled (col ^= (row&7)<<4); sB's
// swizzle is applied by pre-swizzling the per-lane GLOBAL source address
// (global_load_lds dest must stay linear).
__global__ __launch_bounds__(512) void gemm_logits(
    const float* __restrict__ A,          // [Mn, Fn] fp32
    const unsigned short* __restrict__ Wb,// [Vn, Fn] bf16
    const float* __restrict__ bias,
    float* __restrict__ C)                // [Mn, Vn] fp32
{
    __shared__ unsigned short sA[128 * 64];   // 16 KB
    __shared__ unsigned short sB[256 * 64];   // 32 KB
    const int tid  = threadIdx.x;
    const int wid  = tid >> 6, lane = tid & 63;
    const int quad = lane >> 4, c16 = lane & 15;
    const int m0 = blockIdx.x * 128;
    const int wm = (wid & 1) * 64;
    const int wn = (wid >> 1) * 64;

    f32x4 acc[4][4] = {};

    // A staging: thread -> (row, 16-elem k chunk)
    const int arow = tid >> 2;                 // 0..127
    const int akq  = (tid & 3) << 4;           // elem offset 0/16/32/48
    const float* aPtr = A + (size_t)(m0 + arow) * Fn + akq;
    const int aswz = (arow & 7) << 4;
    char* sAbase = (char*)sA + arow * 128;
    const int ab0 = (akq * 2) ^ aswz;          // byte cols of the two 16B chunks
    const int ab1 = (akq * 2 + 16) ^ aswz;

    // W staging via global_load_lds: wave covers 8 rows x 128B per instr.
    const int wrow8 = lane >> 3;                       // row within 8-row group
    const int wcol  = ((lane & 7) << 4) ^ (wrow8 << 4);// pre-swizzled source col

    for (int k0 = 0; k0 < Fn; k0 += 64) {
        // ---- stage W (async, no VALU) ----
        #pragma unroll
        for (int i = 0; i < 4; ++i) {
            const int rbase = wid * 32 + i * 8;
            const unsigned short* g = Wb + (size_t)(rbase + wrow8) * Fn + k0;
            __builtin_amdgcn_global_load_lds(
                (const __attribute__((address_space(1))) unsigned int*)((const char*)g + wcol),
                (__attribute__((address_space(3))) unsigned int*)((char*)sB + rbase * 128),
                16, 0, 0);
        }
        // ---- stage A (regs -> cvt_pk -> swizzled ds_write) ----
        const float4* ap = reinterpret_cast<const float4*>(aPtr + k0);
        float4 av0 = ap[0], av1 = ap[1], av2 = ap[2], av3 = ap[3];
        uint4 p;
        p.x = cvt_pk_bf16(av0.x, av0.y); p.y = cvt_pk_bf16(av0.z, av0.w);
        p.z = cvt_pk_bf16(av1.x, av1.y); p.w = cvt_pk_bf16(av1.z, av1.w);
        *reinterpret_cast<uint4*>(sAbase + ab0) = p;
        p.x = cvt_pk_bf16(av2.x, av2.y); p.y = cvt_pk_bf16(av2.z, av2.w);
        p.z = cvt_pk_bf16(av3.x, av3.y); p.w = cvt_pk_bf16(av3.z, av3.w);
        *reinterpret_cast<uint4*>(sAbase + ab1) = p;
        __syncthreads();   // drains vmcnt (global_load_lds) + lgkm (ds_write)

        #pragma unroll
        for (int kh = 0; kh < 2; ++kh) {
            const int colq = kh * 64 + quad * 16;
            bf16x8 af[4], bf[4];
            #pragma unroll
            for (int mt = 0; mt < 4; ++mt) {
                const int r = wm + mt * 16 + c16;
                af[mt] = *reinterpret_cast<const bf16x8*>((const char*)sA + r * 128 + (colq ^ ((r & 7) << 4)));
            }
            #pragma unroll
            for (int nt = 0; nt < 4; ++nt) {
                const int r = wn + nt * 16 + c16;
                bf[nt] = *reinterpret_cast<const bf16x8*>((const char*)sB + r * 128 + (colq ^ ((r & 7) << 4)));
            }
            #pragma unroll
            for (int mt = 0; mt < 4; ++mt)
                #pragma unroll
                for (int nt = 0; nt < 4; ++nt)
                    acc[mt][nt] = __builtin_amdgcn_mfma_f32_16x16x32_bf16(af[mt], bf[nt], acc[mt][nt], 0, 0, 0);
        }
        __syncthreads();
    }

    #pragma unroll
    for (int nt = 0; nt < 4; ++nt) {
        const int n = wn + nt * 16 + c16;
        const float bb = bias[n];
        #pragma unroll
        for (int mt = 0; mt < 4; ++mt) {
            const int mbase = m0 + wm + mt * 16 + quad * 4;
            #pragma unroll
            for (int r = 0; r < 4; ++r)
                C[(size_t)(mbase + r) * Vn + n] = acc[mt][nt][r] + bb;
        }
    }
}

// -------- gather+normalize: G[m][l] = (logit[m][ext[l]] - lse[m]) * log2e ----
__global__ __launch_bounds__(256) void gather_g(
    const float* __restrict__ C, const int* __restrict__ targets,
    float* __restrict__ G)
{
    const int wv   = threadIdx.x >> 6;
    const int lane = threadIdx.x & 63;
    const int row  = blockIdx.x * 4 + wv;            // m = b*Tn + t
    const int b    = row >> 11;                      // Tn = 2048
    const int* tg  = targets + b * Sn;
    __shared__ float sRow[4][256];

    const float L2E = 1.4426950408889634f;
    float4 v = reinterpret_cast<const float4*>(C + (size_t)row * Vn)[lane];
    float4 x;
    x.x = v.x * L2E; x.y = v.y * L2E; x.z = v.z * L2E; x.w = v.w * L2E;
    float m = fmaxf(fmaxf(x.x, x.y), fmaxf(x.z, x.w));
    #pragma unroll
    for (int off = 32; off >= 1; off >>= 1) m = fmaxf(m, __shfl_xor(m, off, 64));
    float s = exp2fast(x.x - m) + exp2fast(x.y - m) + exp2fast(x.z - m) + exp2fast(x.w - m);
    #pragma unroll
    for (int off = 32; off >= 1; off >>= 1) s += __shfl_xor(s, off, 64);
    const float lse2 = m + log2fast(s);

    float4 y;
    y.x = x.x - lse2; y.y = x.y - lse2; y.z = x.z - lse2; y.w = x.w - lse2;
    reinterpret_cast<float4*>(sRow[wv])[lane] = y;   // same-wave LDS, no barrier

    float* Grow = G + (size_t)row * Lpad;
    #pragma unroll
    for (int q = 0; q < 8; ++q) {
        int l = q * 64 + lane;
        int e = 0;
        if (l & 1) e = tg[l >> 1];
        Grow[l] = sRow[wv][e];
    }
    // l=512 blank; 513..519 = NEG so ctc_alpha's tail slots read finite junk
    if (lane < 8) Grow[512 + lane] = lane ? NEGF : sRow[wv][0];
}

// ---------------- CTC alpha recursion (log2 domain) --------------------------
// 1 block/batch, 8 waves x 2 slots/lane (slot0 even l = blank, slot1 odd).
// Wave w owns [own_lo, own_hi): wave0 [0,66), wave w>=1 [64w+2, 64w+66).
// Coverage = own_lo(w) - 64 .. own_hi(w)-1 -> left halo of exactly 64 slots
// -> 32 barrier-free steps/chunk. Wave 0's left boundary is permanent -inf
// (never goes stale), so its 62-slot halo deficit is harmless.
__global__ __launch_bounds__(512) void ctc_alpha(
    const float* __restrict__ G, const int* __restrict__ targets,
    const int* __restrict__ ilen, const int* __restrict__ tlen,
    float* __restrict__ loss_b)
{
    const int b = blockIdx.x, tid = threadIdx.x;
    const int w = tid >> 6, j = tid & 63;
    __shared__ float sAl[Ln];
    const float* Gb = G + (size_t)b * Tn * Lpad;
    const int* tg = targets + b * Sn;
    const int len = ilen[b];
    const int tl  = tlen[b];

    const int own_lo = (w == 0) ? 0 : 64 * w + 2;
    const int own_hi = min(64 * w + 66, Ln);
    const int lbase  = 64 * w - 62 + 2 * j;          // even
    const int l0 = lbase, l1 = lbase + 1;
    const int cbase = min(max(l0, 0), 512);          // float2 covers cbase..cbase+1

    const bool own0 = (l0 >= own_lo) && (l0 < own_hi);
    const bool own1 = (l1 >= own_lo) && (l1 < own_hi);
    const bool re0  = (l0 >= 0) && (l0 < Ln) && !own0;
    const bool re1  = (l1 >= 0) && (l1 < Ln) && !own1;
    bool sk1 = false;                                // skip allowed at odd slot
    if (l1 >= 1 && l1 < Ln) { int s = l1 >> 1; sk1 = (s == 0) || (tg[s] != tg[s - 1]); }

    // t = 0 init
    float a0, a1;
    {
        float2 g0 = *reinterpret_cast<const float2*>(Gb + cbase);
        a0 = (l0 == 0) ? g0.x : NEGF;
        a1 = (l1 == 1) ? g0.y : NEGF;
    }
    if (own0) sAl[l0] = a0;
    if (own1) sAl[l1] = a1;
    __syncthreads();
    if (re0) a0 = sAl[l0];
    if (re1) a1 = sAl[l1];
    __syncthreads();

    // prefetch pipeline: rows 1..DQ
    const float* gp = Gb + cbase + Lpad;
    float2 pl[DQ];
    #pragma unroll
    for (int d = 0; d < DQ; ++d) {
        pl[d] = *reinterpret_cast<const float2*>(gp);
        gp += Lpad;
    }   // gp now at row 1+DQ

    const int jm1 = (j + 63) & 63;
    int t = 1;
    for (int chunk = 0; chunk < 64; ++chunk) {
        #pragma unroll
        for (int kk = 0; kk < 32; ++kk, ++t) {
            const int pidx = kk & (DQ - 1);
            float2 g = pl[pidx];
            pl[pidx] = *reinterpret_cast<const float2*>(gp);
            if (t + DQ < Tn - 1) gp += Lpad;         // clamp tail at row Tn-1
            float p = __shfl(a1, jm1, 64);           // old alpha at l0-1
            if (j == 0) p = NEGF;
            if (t < len) {
                float z  = sk1 ? p : NEGF;
                float n0 = g.x + lae2(a0, p);        // even l: {l, l-1}
                float n1 = g.y + lae3(a1, a0, z);    // odd l: {l, l-1, l-2}
                a0 = n0; a1 = n1;
            }
        }
        if (own0) sAl[l0] = a0;
        if (own1) sAl[l1] = a1;
        __syncthreads();
        if (re0) a0 = sAl[l0];
        if (re1) a1 = sAl[l1];
        __syncthreads();
    }

    if (tid == 0) {
        float e1 = sAl[2 * tl];
        float e2 = sAl[2 * tl - 1];
        loss_b[b] = -0.6931471805599453f * lae2(e1, e2) / (float)tl;
    }
}

// ---------------- final mean over batch -------------------------------------
__global__ void final_reduce(const float* __restrict__ loss_b, float* __restrict__ out)
{
    const int lane = threadIdx.x;
    float v = (lane < Bn) ? loss_b[lane] : 0.0f;
    #pragma unroll
    for (int off = 32; off >= 1; off >>= 1) v += __shfl_xor(v, off, 64);
    if (lane == 0) out[0] = v * (1.0f / Bn);
}

extern "C" void kernel_launch(void* const* d_in, const int* in_sizes, int n_in,
                              void* d_out, int out_size, void* d_ws, size_t ws_size,
                              hipStream_t stream) {
    const float* feat = (const float*)d_in[0];
    const float* W    = (const float*)d_in[1];
    const float* bias = (const float*)d_in[2];
    const int* tgt    = (const int*)d_in[3];
    const int* il     = (const int*)d_in[4];
    const int* tl     = (const int*)d_in[5];
    float* out = (float*)d_out;

    char* ws = (char*)d_ws;
    float* logits = (float*)ws;                                      // 64 MB
    size_t off_g  = (size_t)Mn * Vn * sizeof(float);
    float* G      = (float*)(ws + off_g);                            // 136 MB
    float* lossb  = (float*)(ws + off_g + (size_t)Mn * Lpad * sizeof(float));
    // Wb (512 KB) aliases the head of G: dead before gather_g writes G.
    unsigned short* Wb = (unsigned short*)G;

    wcvt<<<(Vn * Fn) / 1024, 256, 0, stream>>>(W, Wb);
    gemm_logits<<<Mn / 128, 512, 0, stream>>>(feat, Wb, bias, logits);
    gather_g<<<Mn / 4, 256, 0, stream>>>(logits, tgt, G);
    ctc_alpha<<<Bn, 512, 0, stream>>>(G, tgt, il, tl, lossb);
    final_reduce<<<1, 64, 0, stream>>>(lossb, out);
}

// Round 2
// 662.256 us; speedup vs baseline: 1.2921x; 1.1027x over previous
//
#include <hip/hip_runtime.h>
#include <hip/hip_bf16.h>

using bf16x8 = __attribute__((ext_vector_type(8))) short;
using f32x4  = __attribute__((ext_vector_type(4))) float;

constexpr int Bn = 32;          // batch
constexpr int Tn = 2048;        // time
constexpr int Fn = 1024;        // feature dim (K)
constexpr int Vn = 256;         // vocab (N)
constexpr int Sn = 256;         // target len
constexpr int Ln = 2 * Sn + 1;  // 513 extended labels
constexpr int Mn = Bn * Tn;     // 65536 GEMM rows
constexpr int G2P = 272;        // compact G row: [blank, y[tg[0..255]]], padded
constexpr int DQ = 16;          // prefetch depth (32-step chunks % 16 == 0)

#define NEGF (-1e30f)

__device__ __forceinline__ float exp2fast(float x) { return __builtin_amdgcn_exp2f(x); }
__device__ __forceinline__ float log2fast(float x) { return __builtin_amdgcn_logf(x); }

// v_cvt_pk_bf16_f32: RNE, src0 -> low half (1 instr for 2 elems)
__device__ __forceinline__ unsigned int cvt_pk_bf16(float lo, float hi) {
    unsigned int r;
    asm("v_cvt_pk_bf16_f32 %0, %1, %2" : "=v"(r) : "v"(lo), "v"(hi));
    return r;
}

// log-add-exp in log2 domain; max term's exp2 folded to the 1.0f literal.
__device__ __forceinline__ float lae2(float x, float y) {
    float m = fmaxf(x, y);
    float d = fminf(x, y) - m;
    return m + log2fast(1.0f + exp2fast(d));
}
__device__ __forceinline__ float lae3(float x, float y, float z) {
    float m  = fmaxf(fmaxf(x, y), z);              // v_max3_f32
    float md = __builtin_amdgcn_fmed3f(x, y, z);   // v_med3_f32
    float mn = fminf(fminf(x, y), z);              // v_min3_f32
    return m + log2fast(1.0f + exp2fast(md - m) + exp2fast(mn - m));
}

// ---------------- W fp32 -> bf16 pre-convert ---------------------------------
__global__ __launch_bounds__(256) void wcvt(const float* __restrict__ W,
                                            unsigned short* __restrict__ Wb)
{
    const int idx = (blockIdx.x * 256 + threadIdx.x) * 4;
    float4 v = *reinterpret_cast<const float4*>(W + idx);
    uint2 p;
    p.x = cvt_pk_bf16(v.x, v.y);
    p.y = cvt_pk_bf16(v.z, v.w);
    *reinterpret_cast<uint2*>(Wb + idx) = p;
}

// ------- GEMM + fused log-softmax + CTC gather -> compact G2 -----------------
// 512 threads (8 waves: 2 wm x 4 wn), tile 128x256 (= all vocab cols), BK=64.
// Epilogue: bias add, row max/sum via 2x2KB LDS cross-wave reduce, then dump
// normalized rows (log2 domain) to LDS in two 64-row halves and gather-write
// G2[m] = [blank, y[tg[0]], ..., y[tg[255]]].
__global__ __launch_bounds__(512) void gemm_ctc(
    const float* __restrict__ A,          // [Mn, Fn] fp32
    const unsigned short* __restrict__ Wb,// [Vn, Fn] bf16
    const float* __restrict__ bias,
    const int* __restrict__ targets,
    float* __restrict__ G2)               // [Mn, G2P] fp32
{
    __shared__ char smem[70144];
    unsigned short* sA = (unsigned short*)smem;            // 16384 B (main)
    unsigned short* sB = (unsigned short*)(smem + 16384);  // 32768 B (main)
    float* yL    = (float*)smem;                           // 64*258*4 = 66048 B (epilogue)
    float* sRedA = (float*)(smem + 66048);                 // 2048 B
    float* sRedB = (float*)(smem + 68096);                 // 2048 B

    const int tid  = threadIdx.x;
    const int wid  = tid >> 6, lane = tid & 63;
    const int quad = lane >> 4, c16 = lane & 15;
    const int m0 = blockIdx.x * 128;
    const int wm = (wid & 1) * 64;
    const int wn = (wid >> 1) * 64;

    f32x4 acc[4][4] = {};

    // A staging: thread -> (row, 16-elem k chunk)
    const int arow = tid >> 2;
    const int akq  = (tid & 3) << 4;
    const float* aPtr = A + (size_t)(m0 + arow) * Fn + akq;
    const int aswz = (arow & 7) << 4;
    char* sAbase = (char*)sA + arow * 128;
    const int ab0 = (akq * 2) ^ aswz;
    const int ab1 = (akq * 2 + 16) ^ aswz;

    // W staging via global_load_lds: wave covers 8 rows x 128B per instr.
    const int wrow8 = lane >> 3;
    const int wcol  = ((lane & 7) << 4) ^ (wrow8 << 4);

    for (int k0 = 0; k0 < Fn; k0 += 64) {
        #pragma unroll
        for (int i = 0; i < 4; ++i) {
            const int rbase = wid * 32 + i * 8;
            const unsigned short* g = Wb + (size_t)(rbase + wrow8) * Fn + k0;
            __builtin_amdgcn_global_load_lds(
                (const __attribute__((address_space(1))) unsigned int*)((const char*)g + wcol),
                (__attribute__((address_space(3))) unsigned int*)((char*)sB + rbase * 128),
                16, 0, 0);
        }
        const float4* ap = reinterpret_cast<const float4*>(aPtr + k0);
        float4 av0 = ap[0], av1 = ap[1], av2 = ap[2], av3 = ap[3];
        uint4 p;
        p.x = cvt_pk_bf16(av0.x, av0.y); p.y = cvt_pk_bf16(av0.z, av0.w);
        p.z = cvt_pk_bf16(av1.x, av1.y); p.w = cvt_pk_bf16(av1.z, av1.w);
        *reinterpret_cast<uint4*>(sAbase + ab0) = p;
        p.x = cvt_pk_bf16(av2.x, av2.y); p.y = cvt_pk_bf16(av2.z, av2.w);
        p.z = cvt_pk_bf16(av3.x, av3.y); p.w = cvt_pk_bf16(av3.z, av3.w);
        *reinterpret_cast<uint4*>(sAbase + ab1) = p;
        __syncthreads();

        #pragma unroll
        for (int kh = 0; kh < 2; ++kh) {
            const int colq = kh * 64 + quad * 16;
            bf16x8 af[4], bf[4];
            #pragma unroll
            for (int mt = 0; mt < 4; ++mt) {
                const int r = wm + mt * 16 + c16;
                af[mt] = *reinterpret_cast<const bf16x8*>((const char*)sA + r * 128 + (colq ^ ((r & 7) << 4)));
            }
            #pragma unroll
            for (int nt = 0; nt < 4; ++nt) {
                const int r = wn + nt * 16 + c16;
                bf[nt] = *reinterpret_cast<const bf16x8*>((const char*)sB + r * 128 + (colq ^ ((r & 7) << 4)));
            }
            #pragma unroll
            for (int mt = 0; mt < 4; ++mt)
                #pragma unroll
                for (int nt = 0; nt < 4; ++nt)
                    acc[mt][nt] = __builtin_amdgcn_mfma_f32_16x16x32_bf16(af[mt], bf[nt], acc[mt][nt], 0, 0, 0);
        }
        __syncthreads();
    }

    // ---------------- fused epilogue ----------------
    const float L2E = 1.4426950408889634f;
    const int wng = wid >> 1;

    float bv[4];
    #pragma unroll
    for (int nt = 0; nt < 4; ++nt) bv[nt] = bias[wn + nt * 16 + c16];
    #pragma unroll
    for (int mt = 0; mt < 4; ++mt)
        #pragma unroll
        for (int nt = 0; nt < 4; ++nt)
            #pragma unroll
            for (int r = 0; r < 4; ++r)
                acc[mt][nt][r] += bv[nt];

    // row max: local over nt, reduce over c16 lanes, cross-wave via sRedA
    float rmx[4][4];
    #pragma unroll
    for (int mt = 0; mt < 4; ++mt)
        #pragma unroll
        for (int r = 0; r < 4; ++r) {
            float m = fmaxf(fmaxf(acc[mt][0][r], acc[mt][1][r]),
                            fmaxf(acc[mt][2][r], acc[mt][3][r]));
            #pragma unroll
            for (int off = 8; off >= 1; off >>= 1) m = fmaxf(m, __shfl_xor(m, off, 64));
            rmx[mt][r] = m;
        }
    if (c16 == 0) {
        #pragma unroll
        for (int mt = 0; mt < 4; ++mt)
            #pragma unroll
            for (int r = 0; r < 4; ++r)
                sRedA[(wm + mt * 16 + quad * 4 + r) * 4 + wng] = rmx[mt][r];
    }
    __syncthreads();

    float mL[4][4], sm[4][4];
    #pragma unroll
    for (int mt = 0; mt < 4; ++mt)
        #pragma unroll
        for (int r = 0; r < 4; ++r) {
            const int row = wm + mt * 16 + quad * 4 + r;
            float4 mp = ((const float4*)sRedA)[row];
            mL[mt][r] = fmaxf(fmaxf(mp.x, mp.y), fmaxf(mp.z, mp.w)) * L2E;
            float s = 0.0f;
            #pragma unroll
            for (int nt = 0; nt < 4; ++nt)
                s += exp2fast(fmaf(acc[mt][nt][r], L2E, -mL[mt][r]));
            #pragma unroll
            for (int off = 8; off >= 1; off >>= 1) s += __shfl_xor(s, off, 64);
            sm[mt][r] = s;
        }
    if (c16 == 0) {
        #pragma unroll
        for (int mt = 0; mt < 4; ++mt)
            #pragma unroll
            for (int r = 0; r < 4; ++r)
                sRedB[(wm + mt * 16 + quad * 4 + r) * 4 + wng] = sm[mt][r];
    }
    __syncthreads();

    float cr[4][4];
    #pragma unroll
    for (int mt = 0; mt < 4; ++mt)
        #pragma unroll
        for (int r = 0; r < 4; ++r) {
            const int row = wm + mt * 16 + quad * 4 + r;
            float4 sp = ((const float4*)sRedB)[row];
            cr[mt][r] = -(mL[mt][r] + log2fast((sp.x + sp.y) + (sp.z + sp.w)));
        }

    // two-half dump + gather-write of compact G2
    const int* tg = targets + (m0 >> 11) * Sn;
    const int rl = tid >> 3, c0 = tid & 7;
    #pragma unroll
    for (int h = 0; h < 2; ++h) {
        if ((wid & 1) == h) {
            #pragma unroll
            for (int mt = 0; mt < 4; ++mt)
                #pragma unroll
                for (int nt = 0; nt < 4; ++nt)
                    #pragma unroll
                    for (int r = 0; r < 4; ++r)
                        yL[(mt * 16 + quad * 4 + r) * 258 + wn + nt * 16 + c16] =
                            fmaf(acc[mt][nt][r], L2E, cr[mt][r]);
        }
        __syncthreads();
        {
            const size_t gbase = (size_t)(m0 + h * 64 + rl) * G2P;
            const float* yrow = yL + rl * 258;
            for (int k = 0; k < 33; ++k) {
                const int c = c0 + k * 8;
                if (c < 257) {
                    const int src = (c == 0) ? 0 : tg[c - 1];
                    G2[gbase + c] = yrow[src];
                }
            }
        }
        __syncthreads();
    }
}

// ---------------- CTC alpha recursion (log2 domain) --------------------------
// 1 block/batch, 8 waves x 2 slots/lane. Per-step neighbor exchange is a
// v_mov_b32_dpp wave_shr:1 (lane j <- lane j-1), bound_ctrl off with old=NEGF
// so lane 0 gets the -inf boundary for free. No LDS in the inner loop.
__global__ __launch_bounds__(512) void ctc_alpha(
    const float* __restrict__ G2, const int* __restrict__ targets,
    const int* __restrict__ ilen, const int* __restrict__ tlen,
    float* __restrict__ loss_b)
{
    const int b = blockIdx.x, tid = threadIdx.x;
    const int w = tid >> 6, j = tid & 63;
    __shared__ float sAl[Ln];
    const float* __restrict__ Gb = G2 + (size_t)b * Tn * G2P;
    const int* tg = targets + b * Sn;
    const int len = ilen[b];
    const int tl  = tlen[b];

    const int own_lo = (w == 0) ? 0 : 64 * w + 2;
    const int own_hi = min(64 * w + 66, Ln);
    const int lbase  = 64 * w - 62 + 2 * j;          // even
    const int l0 = lbase, l1 = lbase + 1;
    const int s_c = min(max(32 * w - 31 + j, 0), Sn - 1);

    const bool own0 = (l0 >= own_lo) && (l0 < own_hi);
    const bool own1 = (l1 >= own_lo) && (l1 < own_hi);
    const bool re0  = (l0 >= 0) && (l0 < Ln) && !own0;
    const bool re1  = (l1 >= 0) && (l1 < Ln) && !own1;
    bool sk1 = false;
    if (l1 >= 1 && l1 < Ln) { int s = l1 >> 1; sk1 = (s == 0) || (tg[s] != tg[s - 1]); }

    // t = 0 init
    float a0, a1;
    {
        float bl0 = Gb[0];
        float od0 = Gb[1 + s_c];
        a0 = (l0 == 0) ? bl0 : NEGF;
        a1 = (l1 == 1) ? od0 : NEGF;
    }
    if (own0) sAl[l0] = a0;
    if (own1) sAl[l1] = a1;
    __syncthreads();
    if (re0) a0 = sAl[l0];
    if (re1) a1 = sAl[l1];
    __syncthreads();

    // prefetch rows 1..DQ (blank + own odd col); unconditional advance, G2 has
    // slack rows after the end so tail loads are in-bounds (never consumed).
    unsigned oB = G2P, oO = G2P + 1 + s_c;
    float plB[DQ], plO[DQ];
    #pragma unroll
    for (int d = 0; d < DQ; ++d) {
        plB[d] = Gb[oB]; plO[d] = Gb[oO];
        oB += G2P; oO += G2P;
    }

    const int NEGI = __float_as_int(NEGF);
    int t = 1;
    for (int chunk = 0; chunk < 64; ++chunk) {
        #pragma unroll
        for (int kk = 0; kk < 32; ++kk, ++t) {
            const int pidx = kk & (DQ - 1);
            float gb = plB[pidx], go = plO[pidx];
            plB[pidx] = Gb[oB]; plO[pidx] = Gb[oO];
            oB += G2P; oO += G2P;
            float p = __int_as_float(
                __builtin_amdgcn_update_dpp(NEGI, __float_as_int(a1), 0x138, 0xf, 0xf, false));
            if (t < len) {
                float z  = sk1 ? p : NEGF;
                float n0 = gb + lae2(a0, p);         // even l: {l, l-1}
                float n1 = go + lae3(a1, a0, z);     // odd l: {l, l-1, l-2}
                a0 = n0; a1 = n1;
            }
        }
        if (own0) sAl[l0] = a0;
        if (own1) sAl[l1] = a1;
        __syncthreads();
        if (re0) a0 = sAl[l0];
        if (re1) a1 = sAl[l1];
        __syncthreads();
    }

    if (tid == 0) {
        float e1 = sAl[2 * tl];
        float e2 = sAl[2 * tl - 1];
        loss_b[b] = -0.6931471805599453f * lae2(e1, e2) / (float)tl;
    }
}

// ---------------- final mean over batch -------------------------------------
__global__ void final_reduce(const float* __restrict__ loss_b, float* __restrict__ out)
{
    const int lane = threadIdx.x;
    float v = (lane < Bn) ? loss_b[lane] : 0.0f;
    #pragma unroll
    for (int off = 32; off >= 1; off >>= 1) v += __shfl_xor(v, off, 64);
    if (lane == 0) out[0] = v * (1.0f / Bn);
}

extern "C" void kernel_launch(void* const* d_in, const int* in_sizes, int n_in,
                              void* d_out, int out_size, void* d_ws, size_t ws_size,
                              hipStream_t stream) {
    const float* feat = (const float*)d_in[0];
    const float* W    = (const float*)d_in[1];
    const float* bias = (const float*)d_in[2];
    const int* tgt    = (const int*)d_in[3];
    const int* il     = (const int*)d_in[4];
    const int* tl     = (const int*)d_in[5];
    float* out = (float*)d_out;

    char* ws = (char*)d_ws;
    float* G2 = (float*)ws;                                   // 71.3 MB
    size_t g2b = (size_t)Mn * G2P * sizeof(float) + 32768;    // + prefetch slack
    unsigned short* Wb = (unsigned short*)(ws + g2b);         // 512 KB
    float* lossb = (float*)(ws + g2b + (size_t)Vn * Fn * sizeof(unsigned short));

    wcvt<<<(Vn * Fn) / 1024, 256, 0, stream>>>(W, Wb);
    gemm_ctc<<<Mn / 128, 512, 0, stream>>>(feat, Wb, bias, tgt, G2);
    ctc_alpha<<<Bn, 512, 0, stream>>>(G2, tgt, il, tl, lossb);
    final_reduce<<<1, 64, 0, stream>>>(lossb, out);
}

// Round 3
// 564.432 us; speedup vs baseline: 1.5160x; 1.1733x over previous
//
#include <hip/hip_runtime.h>
#include <hip/hip_bf16.h>

using bf16x8 = __attribute__((ext_vector_type(8))) short;
using f32x4  = __attribute__((ext_vector_type(4))) float;

constexpr int Bn = 32;          // batch
constexpr int Tn = 2048;        // time
constexpr int Fn = 1024;        // feature dim (K)
constexpr int Vn = 256;         // vocab (N)
constexpr int Sn = 256;         // target len
constexpr int Ln = 2 * Sn + 1;  // 513 extended labels
constexpr int Mn = Bn * Tn;     // 65536 GEMM rows
constexpr int G2P = 272;        // compact G row: [blank, y[tg[0..255]]], padded
constexpr int DQ = 16;          // prefetch depth (32-step chunks % 16 == 0)
constexpr int ABP = 520;        // alpha/beta buffer row pad

#define NEGF (-1e30f)

__device__ __forceinline__ float exp2fast(float x) { return __builtin_amdgcn_exp2f(x); }
__device__ __forceinline__ float log2fast(float x) { return __builtin_amdgcn_logf(x); }

// v_cvt_pk_bf16_f32: RNE, src0 -> low half (1 instr for 2 elems)
__device__ __forceinline__ unsigned int cvt_pk_bf16(float lo, float hi) {
    unsigned int r;
    asm("v_cvt_pk_bf16_f32 %0, %1, %2" : "=v"(r) : "v"(lo), "v"(hi));
    return r;
}

// log-add-exp in log2 domain; max term's exp2 folded to the 1.0f literal.
__device__ __forceinline__ float lae2(float x, float y) {
    float m = fmaxf(x, y);
    float d = fminf(x, y) - m;
    return m + log2fast(1.0f + exp2fast(d));
}
__device__ __forceinline__ float lae3(float x, float y, float z) {
    float m  = fmaxf(fmaxf(x, y), z);              // v_max3_f32
    float md = __builtin_amdgcn_fmed3f(x, y, z);   // v_med3_f32
    float mn = fminf(fminf(x, y), z);              // v_min3_f32
    return m + log2fast(1.0f + exp2fast(md - m) + exp2fast(mn - m));
}

// ---------------- W fp32 -> bf16 pre-convert ---------------------------------
__global__ __launch_bounds__(256) void wcvt(const float* __restrict__ W,
                                            unsigned short* __restrict__ Wb)
{
    const int idx = (blockIdx.x * 256 + threadIdx.x) * 4;
    float4 v = *reinterpret_cast<const float4*>(W + idx);
    uint2 p;
    p.x = cvt_pk_bf16(v.x, v.y);
    p.y = cvt_pk_bf16(v.z, v.w);
    *reinterpret_cast<uint2*>(Wb + idx) = p;
}

// ------- GEMM + fused log-softmax + CTC gather -> compact G2 -----------------
// 512 threads (8 waves: 2 wm x 4 wn), tile 128x256 (all vocab cols), BK=64.
// sB (W) double-buffered: global_load_lds for k+1 issued during k's MFMA.
// A prefetched to regs during MFMA, cvt_pk->ds_write after the barrier.
__global__ __launch_bounds__(512, 4) void gemm_ctc(
    const float* __restrict__ A,          // [Mn, Fn] fp32
    const unsigned short* __restrict__ Wb,// [Vn, Fn] bf16
    const float* __restrict__ bias,
    const int* __restrict__ targets,
    float* __restrict__ G2)               // [Mn, G2P] fp32
{
    __shared__ char smem[81920];
    unsigned short* sA = (unsigned short*)smem;            // 16 KB (main)
    unsigned short* sB = (unsigned short*)(smem + 16384);  // 2 x 32 KB (main)
    float* yL    = (float*)smem;                           // 64*258*4 B (epilogue)
    float* sRedA = (float*)(smem + 66048);                 // 2 KB
    float* sRedB = (float*)(smem + 68096);                 // 2 KB

    const int tid  = threadIdx.x;
    const int wid  = tid >> 6, lane = tid & 63;
    const int quad = lane >> 4, c16 = lane & 15;
    const int m0 = blockIdx.x * 128;
    const int wm = (wid & 1) * 64;
    const int wn = (wid >> 1) * 64;

    f32x4 acc[4][4] = {};

    // A staging geometry
    const int arow = tid >> 2;
    const int akq  = (tid & 3) << 4;
    const float* aPtr = A + (size_t)(m0 + arow) * Fn + akq;
    const int aswz = (arow & 7) << 4;
    char* sAbase = (char*)sA + arow * 128;
    const int ab0 = (akq * 2) ^ aswz;
    const int ab1 = (akq * 2 + 16) ^ aswz;

    // W staging via global_load_lds: wave covers 8 rows x 128B per instr.
    const int wrow8 = lane >> 3;
    const int wcol  = ((lane & 7) << 4) ^ (wrow8 << 4);

#define ISSUE_W(K0, BUF)                                                        \
    _Pragma("unroll")                                                           \
    for (int i = 0; i < 4; ++i) {                                               \
        const int rbase = wid * 32 + i * 8;                                     \
        const unsigned short* g = Wb + (size_t)(rbase + wrow8) * Fn + (K0);     \
        __builtin_amdgcn_global_load_lds(                                       \
            (const __attribute__((address_space(1))) unsigned int*)((const char*)g + wcol), \
            (__attribute__((address_space(3))) unsigned int*)((char*)sB + (BUF) * 32768 + rbase * 128), \
            16, 0, 0);                                                          \
    }

    // prologue: stage tile 0
    ISSUE_W(0, 0);
    {
        const float4* ap = reinterpret_cast<const float4*>(aPtr);
        float4 av0 = ap[0], av1 = ap[1], av2 = ap[2], av3 = ap[3];
        uint4 p;
        p.x = cvt_pk_bf16(av0.x, av0.y); p.y = cvt_pk_bf16(av0.z, av0.w);
        p.z = cvt_pk_bf16(av1.x, av1.y); p.w = cvt_pk_bf16(av1.z, av1.w);
        *reinterpret_cast<uint4*>(sAbase + ab0) = p;
        p.x = cvt_pk_bf16(av2.x, av2.y); p.y = cvt_pk_bf16(av2.z, av2.w);
        p.z = cvt_pk_bf16(av3.x, av3.y); p.w = cvt_pk_bf16(av3.z, av3.w);
        *reinterpret_cast<uint4*>(sAbase + ab1) = p;
    }
    __syncthreads();

    for (int it = 0; it < 16; ++it) {
        float4 an0, an1, an2, an3;
        if (it < 15) {
            ISSUE_W((it + 1) * 64, (it + 1) & 1);                 // async, overlaps MFMA
            const float4* ap = reinterpret_cast<const float4*>(aPtr + (it + 1) * 64);
            an0 = ap[0]; an1 = ap[1]; an2 = ap[2]; an3 = ap[3];    // in flight during MFMA
        }
        const char* sBb = (const char*)sB + (it & 1) * 32768;
        #pragma unroll
        for (int kh = 0; kh < 2; ++kh) {
            const int colq = kh * 64 + quad * 16;
            bf16x8 af[4], bf[4];
            #pragma unroll
            for (int mt = 0; mt < 4; ++mt) {
                const int r = wm + mt * 16 + c16;
                af[mt] = *reinterpret_cast<const bf16x8*>((const char*)sA + r * 128 + (colq ^ ((r & 7) << 4)));
            }
            #pragma unroll
            for (int nt = 0; nt < 4; ++nt) {
                const int r = wn + nt * 16 + c16;
                bf[nt] = *reinterpret_cast<const bf16x8*>(sBb + r * 128 + (colq ^ ((r & 7) << 4)));
            }
            #pragma unroll
            for (int mt = 0; mt < 4; ++mt)
                #pragma unroll
                for (int nt = 0; nt < 4; ++nt)
                    acc[mt][nt] = __builtin_amdgcn_mfma_f32_16x16x32_bf16(af[mt], bf[nt], acc[mt][nt], 0, 0, 0);
        }
        __syncthreads();       // sA free; drains W(k+1) lds + A regs
        if (it < 15) {
            uint4 p;
            p.x = cvt_pk_bf16(an0.x, an0.y); p.y = cvt_pk_bf16(an0.z, an0.w);
            p.z = cvt_pk_bf16(an1.x, an1.y); p.w = cvt_pk_bf16(an1.z, an1.w);
            *reinterpret_cast<uint4*>(sAbase + ab0) = p;
            p.x = cvt_pk_bf16(an2.x, an2.y); p.y = cvt_pk_bf16(an2.z, an2.w);
            p.z = cvt_pk_bf16(an3.x, an3.y); p.w = cvt_pk_bf16(an3.z, an3.w);
            *reinterpret_cast<uint4*>(sAbase + ab1) = p;
            __syncthreads();   // tile it+1 ready (lgkm only)
        }
    }
#undef ISSUE_W

    // ---------------- fused epilogue ----------------
    const float L2E = 1.4426950408889634f;
    const int wng = wid >> 1;

    float bv[4];
    #pragma unroll
    for (int nt = 0; nt < 4; ++nt) bv[nt] = bias[wn + nt * 16 + c16];
    #pragma unroll
    for (int mt = 0; mt < 4; ++mt)
        #pragma unroll
        for (int nt = 0; nt < 4; ++nt)
            #pragma unroll
            for (int r = 0; r < 4; ++r)
                acc[mt][nt][r] += bv[nt];

    float rmx[4][4];
    #pragma unroll
    for (int mt = 0; mt < 4; ++mt)
        #pragma unroll
        for (int r = 0; r < 4; ++r) {
            float m = fmaxf(fmaxf(acc[mt][0][r], acc[mt][1][r]),
                            fmaxf(acc[mt][2][r], acc[mt][3][r]));
            #pragma unroll
            for (int off = 8; off >= 1; off >>= 1) m = fmaxf(m, __shfl_xor(m, off, 64));
            rmx[mt][r] = m;
        }
    __syncthreads();           // smem reuse: main-loop buffers dead
    if (c16 == 0) {
        #pragma unroll
        for (int mt = 0; mt < 4; ++mt)
            #pragma unroll
            for (int r = 0; r < 4; ++r)
                sRedA[(wm + mt * 16 + quad * 4 + r) * 4 + wng] = rmx[mt][r];
    }
    __syncthreads();

    float mL[4][4], sm[4][4];
    #pragma unroll
    for (int mt = 0; mt < 4; ++mt)
        #pragma unroll
        for (int r = 0; r < 4; ++r) {
            const int row = wm + mt * 16 + quad * 4 + r;
            float4 mp = ((const float4*)sRedA)[row];
            mL[mt][r] = fmaxf(fmaxf(mp.x, mp.y), fmaxf(mp.z, mp.w)) * L2E;
            float s = 0.0f;
            #pragma unroll
            for (int nt = 0; nt < 4; ++nt)
                s += exp2fast(fmaf(acc[mt][nt][r], L2E, -mL[mt][r]));
            #pragma unroll
            for (int off = 8; off >= 1; off >>= 1) s += __shfl_xor(s, off, 64);
            sm[mt][r] = s;
        }
    if (c16 == 0) {
        #pragma unroll
        for (int mt = 0; mt < 4; ++mt)
            #pragma unroll
            for (int r = 0; r < 4; ++r)
                sRedB[(wm + mt * 16 + quad * 4 + r) * 4 + wng] = sm[mt][r];
    }
    __syncthreads();

    float cr[4][4];
    #pragma unroll
    for (int mt = 0; mt < 4; ++mt)
        #pragma unroll
        for (int r = 0; r < 4; ++r) {
            const int row = wm + mt * 16 + quad * 4 + r;
            float4 sp = ((const float4*)sRedB)[row];
            cr[mt][r] = -(mL[mt][r] + log2fast((sp.x + sp.y) + (sp.z + sp.w)));
        }

    // gather cols hoisted: lane's 5 sweep positions
    const int* tg = targets + (m0 >> 11) * Sn;
    int tgc[5];
    #pragma unroll
    for (int k = 0; k < 5; ++k) {
        const int c = lane + (k << 6);
        tgc[k] = (c == 0) ? 0 : ((c < 257) ? tg[c - 1] : 0);
    }

    // two-half dump + coalesced gather-write (wave-per-row sweeps)
    #pragma unroll
    for (int h = 0; h < 2; ++h) {
        if ((wid & 1) == h) {
            #pragma unroll
            for (int mt = 0; mt < 4; ++mt)
                #pragma unroll
                for (int nt = 0; nt < 4; ++nt)
                    #pragma unroll
                    for (int r = 0; r < 4; ++r)
                        yL[(mt * 16 + quad * 4 + r) * 258 + wn + nt * 16 + c16] =
                            fmaf(acc[mt][nt][r], L2E, cr[mt][r]);
        }
        __syncthreads();
        #pragma unroll
        for (int rr = 0; rr < 8; ++rr) {
            const int row = wid * 8 + rr;
            const float* yrow = yL + row * 258;
            float vals[5];
            #pragma unroll
            for (int k = 0; k < 5; ++k) vals[k] = yrow[tgc[k]];
            float* gout = G2 + (size_t)(m0 + h * 64 + row) * G2P;
            #pragma unroll
            for (int k = 0; k < 4; ++k) gout[lane + (k << 6)] = vals[k];
            if (lane == 0) gout[256] = vals[4];
        }
        __syncthreads();
    }
}

// ---------------- CTC alpha/beta recursion (log2 domain) ---------------------
// Grid 2*Bn: block b<Bn = forward to alpha_1024; b>=Bn = backward to beta_1024.
// 8 waves x 2 slots/lane, DPP neighbor exchange, 32 barrier-free steps/chunk.
__global__ __launch_bounds__(512) void ctc_fb(
    const float* __restrict__ G2, const int* __restrict__ targets,
    const int* __restrict__ ilen, const int* __restrict__ tlen,
    float* __restrict__ abuf)             // [2][Bn][ABP]
{
    const int blk = blockIdx.x;
    const bool bwd = blk >= Bn;
    const int b = bwd ? blk - Bn : blk;
    const int tid = threadIdx.x;
    const int w = tid >> 6, j = tid & 63;
    __shared__ float sAl[Ln];
    const float* __restrict__ Gb = G2 + (size_t)b * Tn * G2P;
    const int* tg = targets + b * Sn;
    const int len = ilen[b];
    const int tl  = tlen[b];
    float* outp = abuf + (size_t)(bwd ? Bn + b : b) * ABP;
    const int NEGI = __float_as_int(NEGF);

    if (!bwd) {
        // ---------------- forward: alpha_0 .. alpha_1024 ----------------
        const int own_lo = (w == 0) ? 0 : 64 * w + 2;
        const int own_hi = min(64 * w + 66, Ln);
        const int lbase  = 64 * w - 62 + 2 * j;
        const int l0 = lbase, l1 = lbase + 1;
        const int s_c = min(max(32 * w - 31 + j, 0), Sn - 1);

        const bool own0 = (l0 >= own_lo) && (l0 < own_hi);
        const bool own1 = (l1 >= own_lo) && (l1 < own_hi);
        const bool re0  = (l0 >= 0) && (l0 < Ln) && !own0;
        const bool re1  = (l1 >= 0) && (l1 < Ln) && !own1;
        bool sk1 = false;
        if (l1 >= 1 && l1 < Ln) { int s = l1 >> 1; sk1 = (s == 0) || (tg[s] != tg[s - 1]); }

        float a0, a1;
        {
            float bl0 = Gb[0];
            float od0 = Gb[1 + s_c];
            a0 = (l0 == 0) ? bl0 : NEGF;
            a1 = (l1 == 1) ? od0 : NEGF;
        }
        if (own0) sAl[l0] = a0;
        if (own1) sAl[l1] = a1;
        __syncthreads();
        if (re0) a0 = sAl[l0];
        if (re1) a1 = sAl[l1];
        __syncthreads();

        unsigned oB = G2P, oO = G2P + 1 + s_c;       // row 1
        float plB[DQ], plO[DQ];
        #pragma unroll
        for (int d = 0; d < DQ; ++d) {
            plB[d] = Gb[oB]; plO[d] = Gb[oO];
            oB += G2P; oO += G2P;
        }

        int t = 1;
        for (int chunk = 0; chunk < 32; ++chunk) {
            #pragma unroll
            for (int kk = 0; kk < 32; ++kk, ++t) {
                const int pidx = kk & (DQ - 1);
                float gb = plB[pidx], go = plO[pidx];
                plB[pidx] = Gb[oB]; plO[pidx] = Gb[oO];
                oB += G2P; oO += G2P;                 // max row 1040 < Tn
                float p = __int_as_float(__builtin_amdgcn_update_dpp(
                    NEGI, __float_as_int(a1), 0x138, 0xf, 0xf, false)); // wave_shr:1
                if (t < len) {
                    float z  = sk1 ? p : NEGF;
                    float n0 = gb + lae2(a0, p);
                    float n1 = go + lae3(a1, a0, z);
                    a0 = n0; a1 = n1;
                }
            }
            if (own0) sAl[l0] = a0;
            if (own1) sAl[l1] = a1;
            __syncthreads();
            if (re0) a0 = sAl[l0];
            if (re1) a1 = sAl[l1];
            __syncthreads();
        }
        if (own0) outp[l0] = a0;
        if (own1) outp[l1] = a1;
    } else {
        // ---------------- backward: beta_2047 -> beta_1024 ----------------
        // lane j: l0 = 64w+2j (even), l1 = l0+1. Own [64w,64w+64), wave7 +512.
        // Right halo 64 slots -> 32 steps/chunk. succ exchange via wave_shl:1.
        const int l0 = 64 * w + 2 * j;
        const int l1 = l0 + 1;
        const int s  = 32 * w + j;                   // l1 >> 1
        const int s_c = min(s, Sn - 1);
        const bool act0 = l0 < Ln, act1 = l1 < Ln;
        const bool own0 = act0 && ((j < 32) || (l0 == Ln - 1));
        const bool own1 = act1 && (j < 32);
        const bool re0 = act0 && !own0, re1 = act1 && !own1;
        bool skb = false;                            // l1 -> l1+2 allowed
        if (s + 1 < Sn) skb = (tg[s + 1] != tg[s]);

        float a0 = (act0 && l0 == 2 * tl)     ? 0.0f : NEGF;   // accept states
        float a1 = (act1 && l1 == 2 * tl - 1) ? 0.0f : NEGF;
        if (own0) sAl[l0] = a0;
        if (own1) sAl[l1] = a1;
        __syncthreads();
        if (re0) a0 = sAl[l0];
        if (re1) a1 = sAl[l1];
        __syncthreads();

        unsigned oB = (unsigned)Tn * G2P;            // row 2048 (slack, dummy)
        unsigned oO = oB + 1 + s_c;
        float plB[DQ], plO[DQ];
        #pragma unroll
        for (int d = 0; d < DQ; ++d) {
            plB[d] = Gb[oB]; plO[d] = Gb[oO];
            oB -= G2P; oO -= G2P;
        }

        int tt = Tn;                                  // frame consumed (tt=2048 is a no-op)
        for (int chunk = 0; chunk < 32; ++chunk) {
            #pragma unroll
            for (int kk = 0; kk < 32; ++kk, --tt) {
                const int pidx = kk & (DQ - 1);
                float gb = plB[pidx], go = plO[pidx];
                plB[pidx] = Gb[oB]; plO[pidx] = Gb[oO];
                oB -= G2P; oO -= G2P;                 // min row 1008 >= 0
                if (tt < len) {                       // uniform branch
                    float c0 = gb + a0;               // g_tt(l0) + beta(l0)
                    float c1 = go + a1;               // g_tt(l1) + beta(l1)
                    float d0 = __int_as_float(__builtin_amdgcn_update_dpp(
                        NEGI, __float_as_int(c0), 0x130, 0xf, 0xf, false)); // wave_shl:1
                    float d1 = __int_as_float(__builtin_amdgcn_update_dpp(
                        NEGI, __float_as_int(c1), 0x130, 0xf, 0xf, false));
                    a0 = lae2(c0, c1);                // even: {l, l+1}
                    a1 = lae3(c1, d0, skb ? d1 : NEGF); // odd: {l, l+1, l+2}
                }
            }
            if (own0) sAl[l0] = a0;
            if (own1) sAl[l1] = a1;
            __syncthreads();
            if (re0) a0 = sAl[l0];
            if (re1) a1 = sAl[l1];
            __syncthreads();
        }
        if (own0) outp[l0] = a0;
        if (own1) outp[l1] = a1;
    }
}

// ------- combine: loss_b[b] = -ln2 * log2( sum_l 2^(alpha+beta) ) / tl -------
__global__ __launch_bounds__(64) void ctc_combine(
    const float* __restrict__ abuf, const int* __restrict__ tlen,
    float* __restrict__ loss_b)
{
    const int b = blockIdx.x, lane = threadIdx.x;
    const float* ap = abuf + (size_t)b * ABP;
    const float* bp = abuf + (size_t)(Bn + b) * ABP;
    float x[9];
    #pragma unroll
    for (int k = 0; k < 9; ++k) {
        const int l = lane + (k << 6);
        x[k] = (l < Ln) ? (ap[l] + bp[l]) : NEGF;
    }
    float m = x[0];
    #pragma unroll
    for (int k = 1; k < 9; ++k) m = fmaxf(m, x[k]);
    #pragma unroll
    for (int off = 32; off >= 1; off >>= 1) m = fmaxf(m, __shfl_xor(m, off, 64));
    float s = 0.0f;
    #pragma unroll
    for (int k = 0; k < 9; ++k) s += exp2fast(x[k] - m);
    #pragma unroll
    for (int off = 32; off >= 1; off >>= 1) s += __shfl_xor(s, off, 64);
    if (lane == 0)
        loss_b[b] = -0.6931471805599453f * (m + log2fast(s)) / (float)tlen[b];
}

// ---------------- final mean over batch -------------------------------------
__global__ void final_reduce(const float* __restrict__ loss_b, float* __restrict__ out)
{
    const int lane = threadIdx.x;
    float v = (lane < Bn) ? loss_b[lane] : 0.0f;
    #pragma unroll
    for (int off = 32; off >= 1; off >>= 1) v += __shfl_xor(v, off, 64);
    if (lane == 0) out[0] = v * (1.0f / Bn);
}

extern "C" void kernel_launch(void* const* d_in, const int* in_sizes, int n_in,
                              void* d_out, int out_size, void* d_ws, size_t ws_size,
                              hipStream_t stream) {
    const float* feat = (const float*)d_in[0];
    const float* W    = (const float*)d_in[1];
    const float* bias = (const float*)d_in[2];
    const int* tgt    = (const int*)d_in[3];
    const int* il     = (const int*)d_in[4];
    const int* tl     = (const int*)d_in[5];
    float* out = (float*)d_out;

    char* ws = (char*)d_ws;
    float* G2 = (float*)ws;                                   // 71.3 MB
    size_t g2b = (size_t)Mn * G2P * sizeof(float) + 32768;    // + prefetch slack
    unsigned short* Wb = (unsigned short*)(ws + g2b);         // 512 KB
    float* abuf  = (float*)(ws + g2b + (size_t)Vn * Fn * sizeof(unsigned short));
    float* lossb = abuf + 2 * Bn * ABP;

    wcvt<<<(Vn * Fn) / 1024, 256, 0, stream>>>(W, Wb);
    gemm_ctc<<<Mn / 128, 512, 0, stream>>>(feat, Wb, bias, tgt, G2);
    ctc_fb<<<2 * Bn, 512, 0, stream>>>(G2, tgt, il, tl, abuf);
    ctc_combine<<<Bn, 64, 0, stream>>>(abuf, tl, lossb);
    final_reduce<<<1, 64, 0, stream>>>(lossb, out);
}

// Round 4
// 562.111 us; speedup vs baseline: 1.5223x; 1.0041x over previous
//
#include <hip/hip_runtime.h>
#include <hip/hip_bf16.h>

using bf16x8 = __attribute__((ext_vector_type(8))) short;
using f32x4  = __attribute__((ext_vector_type(4))) float;

constexpr int Bn = 32;          // batch
constexpr int Tn = 2048;        // time
constexpr int Fn = 1024;        // feature dim (K)
constexpr int Vn = 256;         // vocab (N)
constexpr int Sn = 256;         // target len
constexpr int Ln = 2 * Sn + 1;  // 513 extended labels
constexpr int Mn = Bn * Tn;     // 65536 GEMM rows
constexpr int G2P = 272;        // compact G row: [blank, y[tg[0..255]]], padded
constexpr int DQ = 16;          // prefetch depth (32-step chunks % 16 == 0)
constexpr int ABP = 520;        // alpha/beta buffer row pad

#define NEGF (-1e30f)

__device__ __forceinline__ float exp2fast(float x) { return __builtin_amdgcn_exp2f(x); }
__device__ __forceinline__ float log2fast(float x) { return __builtin_amdgcn_logf(x); }

// v_cvt_pk_bf16_f32: RNE, src0 -> low half (1 instr for 2 elems)
__device__ __forceinline__ unsigned int cvt_pk_bf16(float lo, float hi) {
    unsigned int r;
    asm("v_cvt_pk_bf16_f32 %0, %1, %2" : "=v"(r) : "v"(lo), "v"(hi));
    return r;
}

// log-add-exp in log2 domain; max term's exp2 folded to the 1.0f literal.
__device__ __forceinline__ float lae2(float x, float y) {
    float m = fmaxf(x, y);
    float d = fminf(x, y) - m;
    return m + log2fast(1.0f + exp2fast(d));
}
__device__ __forceinline__ float lae3(float x, float y, float z) {
    float m  = fmaxf(fmaxf(x, y), z);              // v_max3_f32
    float md = __builtin_amdgcn_fmed3f(x, y, z);   // v_med3_f32
    float mn = fminf(fminf(x, y), z);              // v_min3_f32
    return m + log2fast(1.0f + exp2fast(md - m) + exp2fast(mn - m));
}

// ---------------- W fp32 -> bf16 pre-convert ---------------------------------
__global__ __launch_bounds__(256) void wcvt(const float* __restrict__ W,
                                            unsigned short* __restrict__ Wb)
{
    const int idx = (blockIdx.x * 256 + threadIdx.x) * 4;
    float4 v = *reinterpret_cast<const float4*>(W + idx);
    uint2 p;
    p.x = cvt_pk_bf16(v.x, v.y);
    p.y = cvt_pk_bf16(v.z, v.w);
    *reinterpret_cast<uint2*>(Wb + idx) = p;
}

// ------- GEMM + fused log-softmax + CTC gather -> compact G2 -----------------
// 512 threads (8 waves: 2 wm x 4 wn), tile 128x256 (all vocab cols), BK=64.
// Counted-vmcnt pipeline: raw s_barrier + explicit waitcnt; W double-buffered,
// A reg-prefetched 2 tiles ahead; vmcnt never drains to 0 in the steady loop.
__global__ __launch_bounds__(512, 4) void gemm_ctc(
    const float* __restrict__ A,          // [Mn, Fn] fp32
    const unsigned short* __restrict__ Wb,// [Vn, Fn] bf16
    const float* __restrict__ bias,
    const int* __restrict__ targets,
    float* __restrict__ G2)               // [Mn, G2P] fp32
{
    __shared__ char smem[81920];
    unsigned short* sA = (unsigned short*)smem;            // 16 KB (main)
    unsigned short* sB = (unsigned short*)(smem + 16384);  // 2 x 32 KB (main)
    float* yL    = (float*)smem;                           // 64*258*4 B (epilogue)
    float* sRedA = (float*)(smem + 66048);                 // 2 KB
    float* sRedB = (float*)(smem + 68096);                 // 2 KB

    const int tid  = threadIdx.x;
    const int wid  = tid >> 6, lane = tid & 63;
    const int quad = lane >> 4, c16 = lane & 15;
    const int m0 = blockIdx.x * 128;
    const int wm = (wid & 1) * 64;
    const int wn = (wid >> 1) * 64;

    f32x4 acc[4][4] = {};

    // A staging geometry
    const int arow = tid >> 2;
    const int akq  = (tid & 3) << 4;
    const float* aPtr = A + (size_t)(m0 + arow) * Fn + akq;
    const int aswz = (arow & 7) << 4;
    char* sAbase = (char*)sA + arow * 128;
    const int ab0 = (akq * 2) ^ aswz;
    const int ab1 = (akq * 2 + 16) ^ aswz;

    // W staging via global_load_lds: wave covers 8 rows x 128B per instr.
    const int wrow8 = lane >> 3;
    const int wcol  = ((lane & 7) << 4) ^ (wrow8 << 4);

#define ISSUE_W(K0, BUF)                                                        \
    _Pragma("unroll")                                                           \
    for (int i = 0; i < 4; ++i) {                                               \
        const int rbase = wid * 32 + i * 8;                                     \
        const unsigned short* g = Wb + (size_t)(rbase + wrow8) * Fn + (K0);     \
        __builtin_amdgcn_global_load_lds(                                       \
            (const __attribute__((address_space(1))) unsigned int*)((const char*)g + wcol), \
            (__attribute__((address_space(3))) unsigned int*)((char*)sB + (BUF) * 32768 + rbase * 128), \
            16, 0, 0);                                                          \
    }

#define LOAD_A(DST, K0) {                                                       \
        const float4* ap = reinterpret_cast<const float4*>(aPtr + (K0));        \
        DST[0] = ap[0]; DST[1] = ap[1]; DST[2] = ap[2]; DST[3] = ap[3]; }

#define STORE_A(av) { uint4 p;                                                  \
        p.x = cvt_pk_bf16(av[0].x, av[0].y); p.y = cvt_pk_bf16(av[0].z, av[0].w); \
        p.z = cvt_pk_bf16(av[1].x, av[1].y); p.w = cvt_pk_bf16(av[1].z, av[1].w); \
        *reinterpret_cast<uint4*>(sAbase + ab0) = p;                            \
        p.x = cvt_pk_bf16(av[2].x, av[2].y); p.y = cvt_pk_bf16(av[2].z, av[2].w); \
        p.z = cvt_pk_bf16(av[3].x, av[3].y); p.w = cvt_pk_bf16(av[3].z, av[3].w); \
        *reinterpret_cast<uint4*>(sAbase + ab1) = p; }

#define FENCE() asm volatile("" ::: "memory")
#define BARRIER() { FENCE(); __builtin_amdgcn_s_barrier(); FENCE(); }

    float4 apre[2][4];

    // ---- prologue: A(0) -> sA, W(0) -> sB[0]; A(1)/W(1) in flight ----
    LOAD_A(apre[0], 0);
    __builtin_amdgcn_sched_barrier(0);
    ISSUE_W(0, 0);
    __builtin_amdgcn_sched_barrier(0);
    STORE_A(apre[0]);                 // compiler waits A(0) regs (vmcnt(4))
    LOAD_A(apre[1], 64);
    __builtin_amdgcn_sched_barrier(0);
    ISSUE_W(64, 1);
    __builtin_amdgcn_sched_barrier(0);
    asm volatile("s_waitcnt vmcnt(8)" ::: "memory");   // W(0) landed
    asm volatile("s_waitcnt lgkmcnt(0)" ::: "memory"); // sA(0) visible
    __builtin_amdgcn_sched_barrier(0);
    BARRIER();

    #pragma unroll
    for (int k = 0; k < 16; ++k) {
        // ---- phase 1: compute tile k ----
        const char* sBb = (const char*)sB + (k & 1) * 32768;
        #pragma unroll
        for (int kh = 0; kh < 2; ++kh) {
            const int colq = kh * 64 + quad * 16;
            bf16x8 af[4], bf[4];
            #pragma unroll
            for (int mt = 0; mt < 4; ++mt) {
                const int r = wm + mt * 16 + c16;
                af[mt] = *reinterpret_cast<const bf16x8*>((const char*)sA + r * 128 + (colq ^ ((r & 7) << 4)));
            }
            #pragma unroll
            for (int nt = 0; nt < 4; ++nt) {
                const int r = wn + nt * 16 + c16;
                bf[nt] = *reinterpret_cast<const bf16x8*>(sBb + r * 128 + (colq ^ ((r & 7) << 4)));
            }
            #pragma unroll
            for (int mt = 0; mt < 4; ++mt)
                #pragma unroll
                for (int nt = 0; nt < 4; ++nt)
                    acc[mt][nt] = __builtin_amdgcn_mfma_f32_16x16x32_bf16(af[mt], bf[nt], acc[mt][nt], 0, 0, 0);
        }
        asm volatile("s_waitcnt lgkmcnt(0)" ::: "memory");  // all sA/sB reads done
        __builtin_amdgcn_sched_barrier(0);
        BARRIER();                                          // barrier1

        // ---- phase 2: stage tile k+1 into sA; issue tile k+2 ----
        if (k < 15) {
            if (k < 14) {
                LOAD_A(apre[k & 1], (k + 2) * 64);
                __builtin_amdgcn_sched_barrier(0);
                ISSUE_W((k + 2) * 64, k & 1);
                __builtin_amdgcn_sched_barrier(0);
            }
            STORE_A(apre[(k + 1) & 1]);    // compiler waits A(k+1) regs
            if (k < 14) { asm volatile("s_waitcnt vmcnt(8)" ::: "memory"); } // W(k+1) landed
            else        { asm volatile("s_waitcnt vmcnt(0)" ::: "memory"); } // W(15) landed
            asm volatile("s_waitcnt lgkmcnt(0)" ::: "memory");               // sA(k+1) visible
            __builtin_amdgcn_sched_barrier(0);
            BARRIER();                                      // barrier2
        }
    }
#undef ISSUE_W
#undef LOAD_A
#undef STORE_A

    // ---------------- fused epilogue ----------------
    const float L2E = 1.4426950408889634f;
    const int wng = wid >> 1;

    float bv[4];
    #pragma unroll
    for (int nt = 0; nt < 4; ++nt) bv[nt] = bias[wn + nt * 16 + c16];
    #pragma unroll
    for (int mt = 0; mt < 4; ++mt)
        #pragma unroll
        for (int nt = 0; nt < 4; ++nt)
            #pragma unroll
            for (int r = 0; r < 4; ++r)
                acc[mt][nt][r] += bv[nt];

    float rmx[4][4];
    #pragma unroll
    for (int mt = 0; mt < 4; ++mt)
        #pragma unroll
        for (int r = 0; r < 4; ++r) {
            float m = fmaxf(fmaxf(acc[mt][0][r], acc[mt][1][r]),
                            fmaxf(acc[mt][2][r], acc[mt][3][r]));
            #pragma unroll
            for (int off = 8; off >= 1; off >>= 1) m = fmaxf(m, __shfl_xor(m, off, 64));
            rmx[mt][r] = m;
        }
    __syncthreads();           // smem reuse: main-loop buffers dead
    if (c16 == 0) {
        #pragma unroll
        for (int mt = 0; mt < 4; ++mt)
            #pragma unroll
            for (int r = 0; r < 4; ++r)
                sRedA[(wm + mt * 16 + quad * 4 + r) * 4 + wng] = rmx[mt][r];
    }
    __syncthreads();

    float mL[4][4], sm[4][4];
    #pragma unroll
    for (int mt = 0; mt < 4; ++mt)
        #pragma unroll
        for (int r = 0; r < 4; ++r) {
            const int row = wm + mt * 16 + quad * 4 + r;
            float4 mp = ((const float4*)sRedA)[row];
            mL[mt][r] = fmaxf(fmaxf(mp.x, mp.y), fmaxf(mp.z, mp.w)) * L2E;
            float s = 0.0f;
            #pragma unroll
            for (int nt = 0; nt < 4; ++nt)
                s += exp2fast(fmaf(acc[mt][nt][r], L2E, -mL[mt][r]));
            #pragma unroll
            for (int off = 8; off >= 1; off >>= 1) s += __shfl_xor(s, off, 64);
            sm[mt][r] = s;
        }
    if (c16 == 0) {
        #pragma unroll
        for (int mt = 0; mt < 4; ++mt)
            #pragma unroll
            for (int r = 0; r < 4; ++r)
                sRedB[(wm + mt * 16 + quad * 4 + r) * 4 + wng] = sm[mt][r];
    }
    __syncthreads();

    float cr[4][4];
    #pragma unroll
    for (int mt = 0; mt < 4; ++mt)
        #pragma unroll
        for (int r = 0; r < 4; ++r) {
            const int row = wm + mt * 16 + quad * 4 + r;
            float4 sp = ((const float4*)sRedB)[row];
            cr[mt][r] = -(mL[mt][r] + log2fast((sp.x + sp.y) + (sp.z + sp.w)));
        }

    // gather cols hoisted: lane's 5 sweep positions
    const int* tg = targets + (m0 >> 11) * Sn;
    int tgc[5];
    #pragma unroll
    for (int k = 0; k < 5; ++k) {
        const int c = lane + (k << 6);
        tgc[k] = (c == 0) ? 0 : ((c < 257) ? tg[c - 1] : 0);
    }

    // two-half dump + coalesced gather-write (wave-per-row sweeps)
    #pragma unroll
    for (int h = 0; h < 2; ++h) {
        if ((wid & 1) == h) {
            #pragma unroll
            for (int mt = 0; mt < 4; ++mt)
                #pragma unroll
                for (int nt = 0; nt < 4; ++nt)
                    #pragma unroll
                    for (int r = 0; r < 4; ++r)
                        yL[(mt * 16 + quad * 4 + r) * 258 + wn + nt * 16 + c16] =
                            fmaf(acc[mt][nt][r], L2E, cr[mt][r]);
        }
        __syncthreads();
        #pragma unroll
        for (int rr = 0; rr < 8; ++rr) {
            const int row = wid * 8 + rr;
            const float* yrow = yL + row * 258;
            float vals[5];
            #pragma unroll
            for (int k = 0; k < 5; ++k) vals[k] = yrow[tgc[k]];
            float* gout = G2 + (size_t)(m0 + h * 64 + row) * G2P;
            #pragma unroll
            for (int k = 0; k < 4; ++k) gout[lane + (k << 6)] = vals[k];
            if (lane == 0) gout[256] = vals[4];
        }
        __syncthreads();
    }
}

// ---------------- CTC alpha/beta recursion (log2 domain) ---------------------
// Grid 2*Bn: block b<Bn = forward to alpha_1024; b>=Bn = backward to beta_1024.
// 8 waves x 2 slots/lane, DPP neighbor exchange, 32 barrier-free steps/chunk.
// Blank column is wave-uniform -> scalar (s_load) prefetch pipeline.
__global__ __launch_bounds__(512) void ctc_fb(
    const float* __restrict__ G2, const int* __restrict__ targets,
    const int* __restrict__ ilen, const int* __restrict__ tlen,
    float* __restrict__ abuf)             // [2][Bn][ABP]
{
    const int blk = blockIdx.x;
    const bool bwd = blk >= Bn;
    const int b = bwd ? blk - Bn : blk;
    const int tid = threadIdx.x;
    const int w = tid >> 6, j = tid & 63;
    __shared__ float sAl[Ln];
    const float* __restrict__ Gb = G2 + (size_t)b * Tn * G2P;
    const int* tg = targets + b * Sn;
    const int len = ilen[b];
    const int tl  = tlen[b];
    float* outp = abuf + (size_t)(bwd ? Bn + b : b) * ABP;
    const int NEGI = __float_as_int(NEGF);

    if (!bwd) {
        // ---------------- forward: alpha_0 .. alpha_1024 ----------------
        const int own_lo = (w == 0) ? 0 : 64 * w + 2;
        const int own_hi = min(64 * w + 66, Ln);
        const int lbase  = 64 * w - 62 + 2 * j;
        const int l0 = lbase, l1 = lbase + 1;
        const int s_c = min(max(32 * w - 31 + j, 0), Sn - 1);

        const bool own0 = (l0 >= own_lo) && (l0 < own_hi);
        const bool own1 = (l1 >= own_lo) && (l1 < own_hi);
        const bool re0  = (l0 >= 0) && (l0 < Ln) && !own0;
        const bool re1  = (l1 >= 0) && (l1 < Ln) && !own1;
        bool sk1 = false;
        if (l1 >= 1 && l1 < Ln) { int s = l1 >> 1; sk1 = (s == 0) || (tg[s] != tg[s - 1]); }

        float a0, a1;
        {
            float bl0 = Gb[0];
            float od0 = Gb[1 + s_c];
            a0 = (l0 == 0) ? bl0 : NEGF;
            a1 = (l1 == 1) ? od0 : NEGF;
        }
        if (own0) sAl[l0] = a0;
        if (own1) sAl[l1] = a1;
        __syncthreads();
        if (re0) a0 = sAl[l0];
        if (re1) a1 = sAl[l1];
        __syncthreads();

        size_t rOB = G2P;                            // uniform blank offset (row 1)
        unsigned oO = G2P + 1 + s_c;                 // per-lane odd offset
        float sgb[DQ], plO[DQ];
        #pragma unroll
        for (int d = 0; d < DQ; ++d) {
            sgb[d] = Gb[rOB]; plO[d] = Gb[oO];
            rOB += G2P; oO += G2P;
        }

        int t = 1;
        for (int chunk = 0; chunk < 32; ++chunk) {
            #pragma unroll
            for (int kk = 0; kk < 32; ++kk, ++t) {
                const int pidx = kk & (DQ - 1);
                float gb = sgb[pidx], go = plO[pidx];
                sgb[pidx] = Gb[rOB]; plO[pidx] = Gb[oO];
                rOB += G2P; oO += G2P;                // max row 1040 < Tn
                float p = __int_as_float(__builtin_amdgcn_update_dpp(
                    NEGI, __float_as_int(a1), 0x138, 0xf, 0xf, false)); // wave_shr:1
                if (t < len) {
                    float z  = sk1 ? p : NEGF;
                    float n0 = gb + lae2(a0, p);
                    float n1 = go + lae3(a1, a0, z);
                    a0 = n0; a1 = n1;
                }
            }
            if (own0) sAl[l0] = a0;
            if (own1) sAl[l1] = a1;
            __syncthreads();
            if (re0) a0 = sAl[l0];
            if (re1) a1 = sAl[l1];
            __syncthreads();
        }
        if (own0) outp[l0] = a0;
        if (own1) outp[l1] = a1;
    } else {
        // ---------------- backward: beta_2047 -> beta_1024 ----------------
        // lane j: l0 = 64w+2j (even), l1 = l0+1. Own [64w,64w+64), wave7 +512.
        // Right halo 64 slots -> 32 steps/chunk. succ exchange via wave_shl:1.
        const int l0 = 64 * w + 2 * j;
        const int l1 = l0 + 1;
        const int s  = 32 * w + j;                   // l1 >> 1
        const int s_c = min(s, Sn - 1);
        const bool act0 = l0 < Ln, act1 = l1 < Ln;
        const bool own0 = act0 && ((j < 32) || (l0 == Ln - 1));
        const bool own1 = act1 && (j < 32);
        const bool re0 = act0 && !own0, re1 = act1 && !own1;
        bool skb = false;                            // l1 -> l1+2 allowed
        if (s + 1 < Sn) skb = (tg[s + 1] != tg[s]);

        float a0 = (act0 && l0 == 2 * tl)     ? 0.0f : NEGF;   // accept states
        float a1 = (act1 && l1 == 2 * tl - 1) ? 0.0f : NEGF;
        if (own0) sAl[l0] = a0;
        if (own1) sAl[l1] = a1;
        __syncthreads();
        if (re0) a0 = sAl[l0];
        if (re1) a1 = sAl[l1];
        __syncthreads();

        size_t rOB = (size_t)Tn * G2P;               // row 2048 (slack, dummy)
        unsigned oO = (unsigned)rOB + 1 + s_c;
        float sgb[DQ], plO[DQ];
        #pragma unroll
        for (int d = 0; d < DQ; ++d) {
            sgb[d] = Gb[rOB]; plO[d] = Gb[oO];
            rOB -= G2P; oO -= G2P;
        }

        int tt = Tn;                                  // frame consumed (tt=2048 is a no-op)
        for (int chunk = 0; chunk < 32; ++chunk) {
            #pragma unroll
            for (int kk = 0; kk < 32; ++kk, --tt) {
                const int pidx = kk & (DQ - 1);
                float gb = sgb[pidx], go = plO[pidx];
                sgb[pidx] = Gb[rOB]; plO[pidx] = Gb[oO];
                rOB -= G2P; oO -= G2P;                // min row 1008 >= 0
                if (tt < len) {                       // uniform branch
                    float c0 = gb + a0;               // g_tt(l0) + beta(l0)
                    float c1 = go + a1;               // g_tt(l1) + beta(l1)
                    float d0 = __int_as_float(__builtin_amdgcn_update_dpp(
                        NEGI, __float_as_int(c0), 0x130, 0xf, 0xf, false)); // wave_shl:1
                    float d1 = __int_as_float(__builtin_amdgcn_update_dpp(
                        NEGI, __float_as_int(c1), 0x130, 0xf, 0xf, false));
                    a0 = lae2(c0, c1);                // even: {l, l+1}
                    a1 = lae3(c1, d0, skb ? d1 : NEGF); // odd: {l, l+1, l+2}
                }
            }
            if (own0) sAl[l0] = a0;
            if (own1) sAl[l1] = a1;
            __syncthreads();
            if (re0) a0 = sAl[l0];
            if (re1) a1 = sAl[l1];
            __syncthreads();
        }
        if (own0) outp[l0] = a0;
        if (own1) outp[l1] = a1;
    }
}

// ------- combine: loss_b[b] = -ln2 * log2( sum_l 2^(alpha+beta) ) / tl -------
__global__ __launch_bounds__(64) void ctc_combine(
    const float* __restrict__ abuf, const int* __restrict__ tlen,
    float* __restrict__ loss_b)
{
    const int b = blockIdx.x, lane = threadIdx.x;
    const float* ap = abuf + (size_t)b * ABP;
    const float* bp = abuf + (size_t)(Bn + b) * ABP;
    float x[9];
    #pragma unroll
    for (int k = 0; k < 9; ++k) {
        const int l = lane + (k << 6);
        x[k] = (l < Ln) ? (ap[l] + bp[l]) : NEGF;
    }
    float m = x[0];
    #pragma unroll
    for (int k = 1; k < 9; ++k) m = fmaxf(m, x[k]);
    #pragma unroll
    for (int off = 32; off >= 1; off >>= 1) m = fmaxf(m, __shfl_xor(m, off, 64));
    float s = 0.0f;
    #pragma unroll
    for (int k = 0; k < 9; ++k) s += exp2fast(x[k] - m);
    #pragma unroll
    for (int off = 32; off >= 1; off >>= 1) s += __shfl_xor(s, off, 64);
    if (lane == 0)
        loss_b[b] = -0.6931471805599453f * (m + log2fast(s)) / (float)tlen[b];
}

// ---------------- final mean over batch -------------------------------------
__global__ void final_reduce(const float* __restrict__ loss_b, float* __restrict__ out)
{
    const int lane = threadIdx.x;
    float v = (lane < Bn) ? loss_b[lane] : 0.0f;
    #pragma unroll
    for (int off = 32; off >= 1; off >>= 1) v += __shfl_xor(v, off, 64);
    if (lane == 0) out[0] = v * (1.0f / Bn);
}

extern "C" void kernel_launch(void* const* d_in, const int* in_sizes, int n_in,
                              void* d_out, int out_size, void* d_ws, size_t ws_size,
                              hipStream_t stream) {
    const float* feat = (const float*)d_in[0];
    const float* W    = (const float*)d_in[1];
    const float* bias = (const float*)d_in[2];
    const int* tgt    = (const int*)d_in[3];
    const int* il     = (const int*)d_in[4];
    const int* tl     = (const int*)d_in[5];
    float* out = (float*)d_out;

    char* ws = (char*)d_ws;
    float* G2 = (float*)ws;                                   // 71.3 MB
    size_t g2b = (size_t)Mn * G2P * sizeof(float) + 32768;    // + prefetch slack
    unsigned short* Wb = (unsigned short*)(ws + g2b);         // 512 KB
    float* abuf  = (float*)(ws + g2b + (size_t)Vn * Fn * sizeof(unsigned short));
    float* lossb = abuf + 2 * Bn * ABP;

    wcvt<<<(Vn * Fn) / 1024, 256, 0, stream>>>(W, Wb);
    gemm_ctc<<<Mn / 128, 512, 0, stream>>>(feat, Wb, bias, tgt, G2);
    ctc_fb<<<2 * Bn, 512, 0, stream>>>(G2, tgt, il, tl, abuf);
    ctc_combine<<<Bn, 64, 0, stream>>>(abuf, tl, lossb);
    final_reduce<<<1, 64, 0, stream>>>(lossb, out);
}